// Round 7
// baseline (12862.062 us; speedup 1.0000x reference)
//
#include <hip/hip_runtime.h>
#include <hip/hip_bf16.h>

// LSTM encoder: B=64, L=2048, D=256, 4D=1024, VOCAB=6000
// R7: zero-comm scan + ASM-PINNED register tier (anti-remat).
//   R5/R6 lesson: the allocator rematerializes loop-invariant loads into the
//   loop regardless of the waves_per_eu budget; pin values with asm "+v".
//   Tiers per wave (64 U-frags): fj0-31 in VGPRs (128 regs, pinned),
//   fj32-47 in LDS (128KB), fj48-63 streamed from L2 in 2 bands of 8.
//   h via XOR-swizzled LDS double buffer, ONE raw s_barrier/step.

#define B_     64
#define L_     2048
#define D_     256
#define G4_    1024
#define VOCAB_ 6000

typedef short    s16x8 __attribute__((ext_vector_type(8)));
typedef float    f32x4 __attribute__((ext_vector_type(4)));
typedef unsigned u32x2 __attribute__((ext_vector_type(2)));
typedef unsigned u32x4 __attribute__((ext_vector_type(4)));

// ---- ws layout (bytes) ----
#define OFF_EMBB   0u            // VOCAB*D bf16 = 3,072,000
#define OFF_WT     3072000u      // W^T [n][k] bf16; REUSED as mask8 after xg
#define OFF_UF     3596288u      // U frag layout = 524,288
#define OFF_XG     4120576u      // [t][g][w][l][64B] = 268,435,456
#define WS_NEED    272556032u

#define SMEM_U     131072        // 8 waves x 16 frags x 1KB
#define SMEM_H     16384         // 2 bufs x 16 rows x 512B (swizzled)
#define SMEM_TOTAL (SMEM_U + SMEM_H)   // 147,456

__global__ void prep_kernel(const float* __restrict__ emb,
                            const float* __restrict__ W,
                            const float* __restrict__ U,
                            __hip_bfloat16* __restrict__ embb,
                            __hip_bfloat16* __restrict__ Wt,
                            __hip_bfloat16* __restrict__ Ufrag) {
  const int stride = gridDim.x * blockDim.x;
  const int i0 = blockIdx.x * blockDim.x + threadIdx.x;
  for (int i = i0; i < VOCAB_ * D_; i += stride)
    embb[i] = __float2bfloat16(emb[i]);
  for (int i = i0; i < D_ * G4_; i += stride) {
    int k = i >> 10;
    int n = i & (G4_ - 1);
    Wt[n * D_ + k] = __float2bfloat16(W[i]);
  }
  // U frag layout: elem i = ((w*64 + fj)*64 + l)*8 + j
  //   fj = kk*8 + s;  s = q*2 + nt
  //   n = q*256 + w*32 + nt*16 + (l&15);  k = kk*32 + (l>>4)*8 + j
  for (int i = i0; i < 8 * 64 * 64 * 8; i += stride) {
    int j  = i & 7;
    int l  = (i >> 3) & 63;
    int fj = (i >> 9) & 63;
    int w  = (i >> 15) & 7;
    int kk = fj >> 3, s = fj & 7;
    int q = s >> 1, nt = s & 1;
    int n = q * 256 + w * 32 + nt * 16 + (l & 15);
    int k = kk * 32 + (l >> 4) * 8 + j;
    Ufrag[i] = __float2bfloat16(U[k * G4_ + n]);
  }
}

// mask8[t*64+b] = (ctx[b][t] != 0) — runs AFTER xg_kernel, overwrites Wt
__global__ void mask_kernel(const int* __restrict__ ctx,
                            unsigned char* __restrict__ m8) {
  const int stride = gridDim.x * blockDim.x;
  for (int i = blockIdx.x * blockDim.x + threadIdx.x; i < B_ * L_; i += stride) {
    int b = i & 63, t = i >> 6;
    m8[t * 64 + b] = (ctx[b * L_ + t] != 0) ? 1 : 0;
  }
}

__device__ inline unsigned pk2(float a, float b) {
  return (unsigned)__bfloat16_as_ushort(__float2bfloat16(a)) |
         ((unsigned)__bfloat16_as_ushort(__float2bfloat16(b)) << 16);
}
__device__ inline float bl(unsigned u) {
  union { unsigned u; float f; } c; c.u = u << 16; return c.f;
}
__device__ inline float bh(unsigned u) {
  union { unsigned u; float f; } c; c.u = u & 0xffff0000u; return c.f;
}
__device__ inline float fsigmoid(float x) { return 1.f / (1.f + __expf(-x)); }
__device__ inline float ftanh(float x)    { return 1.f - 2.f / (__expf(2.f * x) + 1.f); }

// ---- xg precompute: grid 512 = 32 t-chunks x 4 groups x 4 gates ----
__global__ __launch_bounds__(256, 2)
void xg_kernel(const int* __restrict__ ctx,
               const __hip_bfloat16* __restrict__ embb,
               const __hip_bfloat16* __restrict__ Wt,
               char* __restrict__ xg) {
  const int bid = blockIdx.x;
  const int Q   = bid & 3;
  const int g   = (bid >> 2) & 3;
  const int tc  = bid >> 4;
  const int tid = threadIdx.x;
  const int wv  = tid >> 6;
  const int l   = tid & 63;
  const int l15 = l & 15, lhi = l >> 4;
  const int row0 = g * 16;

  s16x8 bfr[8][4];
#pragma unroll
  for (int nt = 0; nt < 4; ++nt) {
    const int n = Q * 256 + wv * 64 + nt * 16 + l15;
    const __hip_bfloat16* wp = Wt + n * D_ + lhi * 8;
#pragma unroll
    for (int kk = 0; kk < 8; ++kk)
      bfr[kk][nt] = *(const s16x8*)(wp + kk * 32);
  }

  for (int tt = 0; tt < 64; ++tt) {
    const int t = tc * 64 + tt;
    const int tok = ctx[(row0 + l15) * L_ + t];
    const __hip_bfloat16* xp = embb + tok * D_ + lhi * 8;
    s16x8 af[8];
#pragma unroll
    for (int kk = 0; kk < 8; ++kk)
      af[kk] = *(const s16x8*)(xp + kk * 32);

    f32x4 acc[4];
#pragma unroll
    for (int nt = 0; nt < 4; ++nt) acc[nt] = (f32x4){0.f, 0.f, 0.f, 0.f};
#pragma unroll
    for (int kk = 0; kk < 8; ++kk)
#pragma unroll
      for (int nt = 0; nt < 4; ++nt)
        acc[nt] = __builtin_amdgcn_mfma_f32_16x16x32_bf16(af[kk], bfr[kk][nt], acc[nt], 0, 0, 0);

#pragma unroll
    for (int nt = 0; nt < 4; ++nt) {
      const int ws = wv * 2 + (nt >> 1);
      const int s  = Q * 2 + (nt & 1);
      u32x2 vv;
      vv.x = pk2(acc[nt][0], acc[nt][1]);
      vv.y = pk2(acc[nt][2], acc[nt][3]);
      char* p = xg + (size_t)(((t * 4 + g) * 8 + ws) * 64 + l) * 64 + s * 8;
      *(u32x2*)p = vv;
    }
  }
}

// ---- scan: 4 WGs x 512 threads (8 waves, 2/EU -> 256-reg budget) ----
__global__ __attribute__((amdgpu_flat_work_group_size(512, 512),
                          amdgpu_waves_per_eu(2, 2)))
void scan_kernel(const float* __restrict__ bias,
                 const __hip_bfloat16* __restrict__ Ufrag,
                 const char* __restrict__ xg,
                 const unsigned char* __restrict__ mask8,
                 float* __restrict__ out) {
  extern __shared__ __align__(16) char smem[];
  const int g   = blockIdx.x;
  const int tid = threadIdx.x;
  const int w   = tid >> 6;            // wave: d in [w*32, w*32+32)
  const int l   = tid & 63;
  const int l15 = l & 15, lhi = l >> 4;
  const int row0 = g * 16;

  const s16x8* uf = (const s16x8*)Ufrag;

  // U register tier: fj 0..31 (kk 0..3) = 128 VGPRs, PINNED (non-remat)
  s16x8 ur[32];
#pragma unroll
  for (int fj = 0; fj < 32; ++fj)
    ur[fj] = uf[(w * 64 + fj) * 64 + l];
#pragma unroll
  for (int fj = 0; fj < 32; ++fj)
    asm volatile("" : "+v"(ur[fj]));          // asm-defined: cannot remat

  // U LDS tier: fj 32..47 (kk 4..5) -> slot w*16 + i
  s16x8* ulds = (s16x8*)smem;
#pragma unroll
  for (int i = 0; i < 16; ++i)
    ulds[(w * 16 + i) * 64 + l] = uf[(w * 64 + 32 + i) * 64 + l];

  // zero h double-buffer
  {
    unsigned* hz = (unsigned*)(smem + SMEM_U);
    for (int i = tid; i < SMEM_H / 4; i += 512) hz[i] = 0;
  }

  // bias per strip s=q*2+nt: d = w*32 + (s&1)*16 + l15  (pinned too)
  float bq[8];
#pragma unroll
  for (int s = 0; s < 8; ++s)
    bq[s] = bias[(s >> 1) * D_ + w * 32 + (s & 1) * 16 + l15];
#pragma unroll
  for (int s = 0; s < 8; ++s)
    asm volatile("" : "+v"(bq[s]));

  float c[8]  = {0.f, 0.f, 0.f, 0.f, 0.f, 0.f, 0.f, 0.f};
  float hp[8] = {0.f, 0.f, 0.f, 0.f, 0.f, 0.f, 0.f, 0.f};

  __syncthreads();

  const char* xgl = xg + ((size_t)(g * 8 + w) * 64 + l) * 64;
  const int swzr = (l15 & 7) << 4;

  for (int t = 0; t < L_; ++t) {
    int iz;
    asm volatile("v_mov_b32 %0, 0" : "=v"(iz));

    // ---- stream band A (fj 48..55): issued at top, consumed at kk6
    s16x8 sb[8];
#pragma unroll
    for (int s = 0; s < 8; ++s)
      sb[s] = uf[(w * 64 + 48 + s) * 64 + l + iz];

    // ---- xg + mask for this step (consumed at elementwise)
    const u32x4* xp = (const u32x4*)(xgl + (size_t)t * 131072);
    union { u32x4 v[4]; unsigned u[16]; } xw;
    xw.v[0] = xp[0]; xw.v[1] = xp[1]; xw.v[2] = xp[2]; xw.v[3] = xp[3];
    const unsigned msk = *(const unsigned*)(mask8 + t * 64 + row0 + lhi * 4 + iz);

    // ---- phase A: h frags kk0..3 from swizzled LDS, MFMA with reg tier
    const char* hb = smem + SMEM_U + (t & 1) * 8192 + l15 * 512;
    f32x4 acc[8];
#pragma unroll
    for (int s = 0; s < 8; ++s) acc[s] = (f32x4){0.f, 0.f, 0.f, 0.f};

    s16x8 hfA[4];
#pragma unroll
    for (int kk = 0; kk < 4; ++kk)
      hfA[kk] = *(const s16x8*)(hb + ((kk * 64 + lhi * 16) ^ swzr));
#pragma unroll
    for (int kk = 0; kk < 4; ++kk)
#pragma unroll
      for (int s = 0; s < 8; ++s)
        acc[s] = __builtin_amdgcn_mfma_f32_16x16x32_bf16(hfA[kk], ur[kk * 8 + s], acc[s], 0, 0, 0);

    // ---- phase B: h frags kk4..7, LDS tier (kk4,5), stream (kk6,7)
    s16x8 hfB[4];
#pragma unroll
    for (int kk = 0; kk < 4; ++kk)
      hfB[kk] = *(const s16x8*)(hb + (((kk + 4) * 64 + lhi * 16) ^ swzr));
#pragma unroll
    for (int b = 0; b < 2; ++b) {
      s16x8 ub[8];
#pragma unroll
      for (int s = 0; s < 8; ++s)
        ub[s] = ulds[(w * 16 + b * 8 + s) * 64 + l + iz];
#pragma unroll
      for (int s = 0; s < 8; ++s)
        acc[s] = __builtin_amdgcn_mfma_f32_16x16x32_bf16(hfB[b], ub[s], acc[s], 0, 0, 0);
    }
#pragma unroll
    for (int s = 0; s < 8; ++s)
      acc[s] = __builtin_amdgcn_mfma_f32_16x16x32_bf16(hfB[2], sb[s], acc[s], 0, 0, 0);

    __builtin_amdgcn_sched_barrier(0);   // keep band B below band-A use
    // ---- stream band B (fj 56..63), reuses sb regs
#pragma unroll
    for (int s = 0; s < 8; ++s)
      sb[s] = uf[(w * 64 + 56 + s) * 64 + l + iz];
#pragma unroll
    for (int s = 0; s < 8; ++s)
      acc[s] = __builtin_amdgcn_mfma_f32_16x16x32_bf16(hfB[3], sb[s], acc[s], 0, 0, 0);

    // ---- elementwise LSTM (8 cells/lane), h write to swizzled buf[(t+1)&1]
    char* hw = smem + SMEM_U + ((t + 1) & 1) * 8192;
#pragma unroll
    for (int nt = 0; nt < 2; ++nt)
#pragma unroll
      for (int r = 0; r < 4; ++r) {
        const int e  = nt * 4 + r;
        const int wi = nt * 2 + (r >> 1);
        const bool hi = (r & 1);
        float x0 = hi ? bh(xw.u[0 + wi])  : bl(xw.u[0 + wi]);
        float x1 = hi ? bh(xw.u[4 + wi])  : bl(xw.u[4 + wi]);
        float x2 = hi ? bh(xw.u[8 + wi])  : bl(xw.u[8 + wi]);
        float x3 = hi ? bh(xw.u[12 + wi]) : bl(xw.u[12 + wi]);
        float gi = acc[0 + nt][r] + x0 + bq[0 + nt];
        float gf = acc[2 + nt][r] + x1 + bq[2 + nt];
        float gc = acc[4 + nt][r] + x2 + bq[4 + nt];
        float go = acc[6 + nt][r] + x3 + bq[6 + nt];
        float i_ = fsigmoid(gi);
        float f_ = fsigmoid(gf);
        float o_ = fsigmoid(go);
        float cn = f_ * c[e] + i_ * ftanh(gc);
        float hn = o_ * ftanh(cn);
        const bool upd = ((msk >> (8 * r)) & 255u) != 0u;
        c[e]  = upd ? cn : c[e];
        hp[e] = upd ? hn : hp[e];
        const int row = lhi * 4 + r;
        const int d   = w * 32 + nt * 16 + l15;
        out[((size_t)(row0 + row) * L_ + t) * D_ + d] = hp[e];
        *(unsigned short*)(hw + row * 512 + ((2 * d) ^ ((row & 7) << 4))) =
            __bfloat16_as_ushort(__float2bfloat16(hp[e]));
      }

    asm volatile("s_waitcnt lgkmcnt(0)" ::: "memory");
    __builtin_amdgcn_s_barrier();
    __builtin_amdgcn_sched_barrier(0);
  }
}

extern "C" void kernel_launch(void* const* d_in, const int* in_sizes, int n_in,
                              void* d_out, int out_size, void* d_ws, size_t ws_size,
                              hipStream_t stream) {
  const int*   ctx  = (const int*)d_in[0];
  const float* emb  = (const float*)d_in[1];
  const float* W    = (const float*)d_in[2];
  const float* U    = (const float*)d_in[3];
  const float* bias = (const float*)d_in[4];
  float* out = (float*)d_out;

  char* ws = (char*)d_ws;
  __hip_bfloat16* embb = (__hip_bfloat16*)(ws + OFF_EMBB);
  __hip_bfloat16* Wt   = (__hip_bfloat16*)(ws + OFF_WT);
  __hip_bfloat16* Uf   = (__hip_bfloat16*)(ws + OFF_UF);
  unsigned char*  m8   = (unsigned char*)(ws + OFF_WT);   // reuse Wt after xg
  char*           xgb  = ws + OFF_XG;

  hipFuncSetAttribute((const void*)scan_kernel,
                      hipFuncAttributeMaxDynamicSharedMemorySize, SMEM_TOTAL);

  prep_kernel<<<1024, 256, 0, stream>>>(emb, W, U, embb, Wt, Uf);
  xg_kernel<<<512, 256, 0, stream>>>(ctx, embb, Wt, xgb);
  mask_kernel<<<128, 256, 0, stream>>>(ctx, m8);           // overwrites Wt (dead)
  scan_kernel<<<4, 512, SMEM_TOTAL, stream>>>(bias, Uf, xgb, m8, out);
}

// Round 9
// 4792.100 us; speedup vs baseline: 2.6840x; 2.6840x over previous
//
#include <hip/hip_runtime.h>
#include <hip/hip_bf16.h>

// LSTM encoder: B=64, L=2048, D=256, 4D=1024, VOCAB=6000
// R9: 4 CUs per row-group, static roles, PROVEN transport, bounded waits.
//   Workers: blockIdx 0..15 -> (g = bid>>2, q = bid&3). Each worker CU owns
//   16 rows x 64 d x 4 gates (256 U-cols, 128KB): 8 frags/wave in VGPRs +
//   8 frags/wave in LDS. No per-step U streaming, no register-tier fights.
//   h exchange: tagged 8B granules {2xbf16,tag} via sc0sc1 (system-coherent,
//   R2/R3-proven). Polls BOUNDED (16384 spins) -> worst case absmax fail,
//   never a hang. Publish is fire-and-forget.
//   Heaters: blockIdx 16..255 run dependent-FMA chains (bounded) and exit
//   when all 16 worker done-flags set -> keeps DPM clocks up during the scan
//   (tests the downclock hypothesis from R1-R7's uniformly ~3x-slow steps).

#define B_     64
#define L_     2048
#define D_     256
#define G4_    1024
#define VOCAB_ 6000

typedef short    s16x8 __attribute__((ext_vector_type(8)));
typedef float    f32x4 __attribute__((ext_vector_type(4)));
typedef unsigned u32x2 __attribute__((ext_vector_type(2)));
typedef unsigned u32x4 __attribute__((ext_vector_type(4)));

// ---- ws layout (bytes) ----
#define OFF_EMBB   0u            // VOCAB*D bf16 = 3,072,000
#define OFF_WT     3072000u      // W^T bf16 (dead after xg; reused as mask8)
#define OFF_UF     3596288u      // U frag layout = 524,288
#define OFF_HTAG   4120576u      // 2 parity x 64 rows x 128 granules x 8B = 131,072
#define OFF_DONE   4251648u      // 16 x u32 worker done flags (+pad) = 64
#define OFF_XG     4251712u      // [t][g][q][em16][p32][Q4] u32 = 268,435,456
#define WS_NEED    272687168u

// ---- scan LDS layout (dynamic) ----
#define ULDS_OFF   0             // 64 slots x 1KB U frags = 65,536
#define SG_OFF     65536         // gates f32 [4][16][66] = 16,896
#define HL_OFF     82432         // h staging 16 rows x 512B (XOR-swizzled) = 8,192
#define ROLE_OFF   90624         // heater stop broadcast
#define SMEM_TOTAL 90752

__global__ void prep_kernel(const float* __restrict__ emb,
                            const float* __restrict__ W,
                            const float* __restrict__ U,
                            __hip_bfloat16* __restrict__ embb,
                            __hip_bfloat16* __restrict__ Wt,
                            __hip_bfloat16* __restrict__ Ufrag) {
  const int stride = gridDim.x * blockDim.x;
  const int i0 = blockIdx.x * blockDim.x + threadIdx.x;
  for (int i = i0; i < VOCAB_ * D_; i += stride)
    embb[i] = __float2bfloat16(emb[i]);
  for (int i = i0; i < D_ * G4_; i += stride) {
    int k = i >> 10;
    int n = i & (G4_ - 1);
    Wt[n * D_ + k] = __float2bfloat16(W[i]);
  }
  // U frags: fr = ((q*8 + w)*8 + kk)*2 + nt, elem i = fr*512 + l*8 + j
  //   n = (w>>1)*256 + q*64 + (w&1)*32 + nt*16 + (l&15)
  //   k = kk*32 + (l>>4)*8 + j
  for (int i = i0; i < 262144; i += stride) {
    int j  = i & 7;
    int l  = (i >> 3) & 63;
    int fr = i >> 9;
    int nt = fr & 1;
    int kk = (fr >> 1) & 7;
    int w  = (fr >> 4) & 7;
    int qq = fr >> 7;
    int n = (w >> 1) * 256 + qq * 64 + (w & 1) * 32 + nt * 16 + (l & 15);
    int k = kk * 32 + (l >> 4) * 8 + j;
    Ufrag[i] = __float2bfloat16(U[k * G4_ + n]);
  }
}

// mask8[t*64+b] = (ctx[b][t] != 0) — runs AFTER xg_kernel, overwrites Wt
__global__ void mask_kernel(const int* __restrict__ ctx,
                            unsigned char* __restrict__ m8) {
  const int stride = gridDim.x * blockDim.x;
  for (int i = blockIdx.x * blockDim.x + threadIdx.x; i < B_ * L_; i += stride) {
    int b = i & 63, t = i >> 6;
    m8[t * 64 + b] = (ctx[b * L_ + t] != 0) ? 1 : 0;
  }
}

__device__ inline unsigned pk2(float a, float b) {
  return (unsigned)__bfloat16_as_ushort(__float2bfloat16(a)) |
         ((unsigned)__bfloat16_as_ushort(__float2bfloat16(b)) << 16);
}
__device__ inline float bl(unsigned u) {
  union { unsigned u; float f; } c; c.u = u << 16; return c.f;
}
__device__ inline float bh(unsigned u) {
  union { unsigned u; float f; } c; c.u = u & 0xffff0000u; return c.f;
}
__device__ inline float fsigmoid(float x) { return 1.f / (1.f + __expf(-x)); }
__device__ inline float ftanh(float x)    { return 1.f - 2.f / (__expf(2.f * x) + 1.f); }

// ---- xg precompute: grid 512 = 32 t-chunks x 4 groups x 4 gates ----
// Output layout: xg[t][g][q][em(16)][p(32)][Q(4)] as u32 = pk2 of d-pair.
__global__ __launch_bounds__(256, 2)
void xg_kernel(const int* __restrict__ ctx,
               const __hip_bfloat16* __restrict__ embb,
               const __hip_bfloat16* __restrict__ Wt,
               unsigned* __restrict__ xgw) {
  const int bid = blockIdx.x;
  const int Q   = bid & 3;
  const int g   = (bid >> 2) & 3;
  const int tc  = bid >> 4;
  const int tid = threadIdx.x;
  const int wv  = tid >> 6;            // == quadrant q of the scan
  const int l   = tid & 63;
  const int l15 = l & 15, lhi = l >> 4;
  const int row0 = g * 16;

  s16x8 bfr[8][4];
#pragma unroll
  for (int nt = 0; nt < 4; ++nt) {
    const int n = Q * 256 + wv * 64 + nt * 16 + l15;
    const __hip_bfloat16* wp = Wt + n * D_ + lhi * 8;
#pragma unroll
    for (int kk = 0; kk < 8; ++kk)
      bfr[kk][nt] = *(const s16x8*)(wp + kk * 32);
  }

  for (int tt = 0; tt < 64; ++tt) {
    const int t = tc * 64 + tt;
    const int tok = ctx[(row0 + l15) * L_ + t];
    const __hip_bfloat16* xp = embb + tok * D_ + lhi * 8;
    s16x8 af[8];
#pragma unroll
    for (int kk = 0; kk < 8; ++kk)
      af[kk] = *(const s16x8*)(xp + kk * 32);

    f32x4 acc[4];
#pragma unroll
    for (int nt = 0; nt < 4; ++nt) acc[nt] = (f32x4){0.f, 0.f, 0.f, 0.f};
#pragma unroll
    for (int kk = 0; kk < 8; ++kk)
#pragma unroll
      for (int nt = 0; nt < 4; ++nt)
        acc[nt] = __builtin_amdgcn_mfma_f32_16x16x32_bf16(af[kk], bfr[kk][nt], acc[nt], 0, 0, 0);

    // pair adjacent cols via shfl, even-col lanes store u32 per (row, pair, Q)
#pragma unroll
    for (int nt = 0; nt < 4; ++nt)
#pragma unroll
      for (int r = 0; r < 4; ++r) {
        float nb = __shfl_xor(acc[nt][r], 1);
        if (!(l15 & 1)) {
          unsigned v = pk2(acc[nt][r], nb);
          int em = lhi * 4 + r;
          int p  = nt * 8 + (l15 >> 1);
          size_t idx = ((((size_t)(t * 4 + g) * 4 + wv) * 16 + em) * 32 + p) * 4 + Q;
          xgw[idx] = v;
        }
      }
  }
}

// ---- scan: 256 WGs x 512 thr; bid 0..15 workers, 16..255 heaters ----
__global__ __launch_bounds__(512, 1)
void scan_kernel(const float* __restrict__ bias,
                 const __hip_bfloat16* __restrict__ Ufrag,
                 const unsigned* __restrict__ xgw,
                 const unsigned char* __restrict__ mask8,
                 unsigned* __restrict__ donef,
                 char* __restrict__ htag,
                 float* __restrict__ out) {
  extern __shared__ __align__(16) char smem[];
  const int bid = blockIdx.x;
  const int tid = threadIdx.x;

  if (bid >= 16) {
    // ---- heater: dependent FMA chains keep DPM clocks up; exit on done
    volatile int* hd = (volatile int*)(smem + ROLE_OFF);
    if (tid == 0) *hd = 0;
    __syncthreads();
    float v0 = (float)(tid + 1), v1 = v0 * 1.1f, v2 = v0 * 1.2f, v3 = v0 * 1.3f;
    for (int it = 0; it < (1 << 15); ++it) {
#pragma unroll
      for (int kk = 0; kk < 128; ++kk) {
        v0 = __builtin_fmaf(v0, 1.0000001f, 1.0e-7f);
        v1 = __builtin_fmaf(v1, 1.0000001f, 1.0e-7f);
        v2 = __builtin_fmaf(v2, 1.0000001f, 1.0e-7f);
        v3 = __builtin_fmaf(v3, 1.0000001f, 1.0e-7f);
      }
      if (tid == 0 && (it & 3) == 0) {
        u32x4 fa, fb, fc, fd;
        asm volatile(
            "global_load_dwordx4 %0, %4, off sc0 sc1\n\t"
            "global_load_dwordx4 %1, %4, off offset:16 sc0 sc1\n\t"
            "global_load_dwordx4 %2, %4, off offset:32 sc0 sc1\n\t"
            "global_load_dwordx4 %3, %4, off offset:48 sc0 sc1\n\t"
            "s_waitcnt vmcnt(0)"
            : "=&v"(fa), "=&v"(fb), "=&v"(fc), "=&v"(fd)
            : "v"(donef) : "memory");
        unsigned mn = fa.x;
        mn = fa.y < mn ? fa.y : mn; mn = fa.z < mn ? fa.z : mn; mn = fa.w < mn ? fa.w : mn;
        mn = fb.x < mn ? fb.x : mn; mn = fb.y < mn ? fb.y : mn;
        mn = fb.z < mn ? fb.z : mn; mn = fb.w < mn ? fb.w : mn;
        mn = fc.x < mn ? fc.x : mn; mn = fc.y < mn ? fc.y : mn;
        mn = fc.z < mn ? fc.z : mn; mn = fc.w < mn ? fc.w : mn;
        mn = fd.x < mn ? fd.x : mn; mn = fd.y < mn ? fd.y : mn;
        mn = fd.z < mn ? fd.z : mn; mn = fd.w < mn ? fd.w : mn;
        if (mn != 0u) *hd = 1;
      }
      if (*hd) break;
    }
    asm volatile("" :: "v"(v0), "v"(v1), "v"(v2), "v"(v3));
    return;
  }

  // ---- worker: g = bid>>2 (row group), q = bid&3 (d-quadrant)
  const int g = bid >> 2;
  const int q = bid & 3;
  const int row0 = g * 16;

  const int w   = tid >> 6;             // wave 0..7: gate Q = w>>1, half = w&1
  const int l   = tid & 63;
  const int l15 = l & 15, lhi = l >> 4;
  const int Q   = w >> 1, sgs = w & 1;
  const int em  = tid >> 5;             // elementwise row 0..15
  const int e5  = tid & 31;             // elementwise d-pair 0..31

  s16x8* ulds = (s16x8*)(smem + ULDS_OFF);
  float* sg   = (float*)(smem + SG_OFF);
  char*  hl   = smem + HL_OFF;

  // ---- U tiers: 8 frags regs (kk0..3) + 8 frags LDS (kk4..7)
  const s16x8* ufb = (const s16x8*)Ufrag + (size_t)((q * 8 + w) * 16) * 64;
  s16x8 ur[8];
#pragma unroll
  for (int jf = 0; jf < 8; ++jf)
    ur[jf] = ufb[jf * 64 + l];
#pragma unroll
  for (int jf = 0; jf < 8; ++jf)
    ulds[(w * 8 + jf) * 64 + l] = ufb[(8 + jf) * 64 + l];

  // bias: bq[Q][b] for d = q*64 + 2*e5 + b
  float bq[4][2];
#pragma unroll
  for (int Qq = 0; Qq < 4; ++Qq) {
    bq[Qq][0] = bias[Qq * 256 + q * 64 + 2 * e5];
    bq[Qq][1] = bias[Qq * 256 + q * 64 + 2 * e5 + 1];
  }

  float cc[2] = {0.f, 0.f}, hh[2] = {0.f, 0.f};
  __syncthreads();                      // ulds staged

  const int prow = w * 2 + (l >> 5);    // this wave's poll row (local 0..15)
  const int pswz = (prow & 7) << 4;

  for (int t = 0; t < L_; ++t) {
    // ---- xg + mask for this step (independent; hidden under poll)
    const u32x4 xq = *(const u32x4*)(xgw +
        (((((size_t)t * 4 + g) * 4 + q) * 16 + em) * 32 + e5) * 4);
    const unsigned char mk = mask8[t * 64 + row0 + em];

    // ---- poll own 2 rows' granules of h(t-1) (sc0sc1, BOUNDED)
    {
      const char* hp = htag + ((t + 1) & 1) * 65536 + (row0 + prow) * 1024 + (l & 31) * 32;
      const unsigned want = (unsigned)t;
      u32x4 qa, qb;
      int spins = 0;
      while (true) {
        asm volatile("global_load_dwordx4 %0, %2, off sc0 sc1\n\t"
                     "global_load_dwordx4 %1, %2, off offset:16 sc0 sc1\n\t"
                     "s_waitcnt vmcnt(0)"
                     : "=&v"(qa), "=&v"(qb) : "v"(hp) : "memory");
        unsigned mn = qa.y < qa.w ? qa.y : qa.w;
        mn = qb.y < mn ? qb.y : mn;
        mn = qb.w < mn ? qb.w : mn;
        if (__all((int)(mn >= want))) break;
        if (++spins > 16384) break;     // fail-safe: wrong answer, never hang
      }
      // stage h to swizzled LDS: row prow, d-channels 8*(l&31)..+7
      union { unsigned u[4]; s16x8 v; } hcv;
      hcv.u[0] = qa.x; hcv.u[1] = qa.z; hcv.u[2] = qb.x; hcv.u[3] = qb.z;
      *(s16x8*)(hl + prow * 512 + (((l & 31) * 16) ^ pswz)) = hcv.v;
    }
    asm volatile("s_waitcnt lgkmcnt(0)" ::: "memory");
    __builtin_amdgcn_s_barrier();       // A: h staged

    // ---- A-frags from swizzled LDS + 16 MFMA (8 kk x 2 n-strips)
    f32x4 acc0 = {0.f, 0.f, 0.f, 0.f}, acc1 = {0.f, 0.f, 0.f, 0.f};
    s16x8 hf[8];
#pragma unroll
    for (int kk = 0; kk < 8; ++kk)
      hf[kk] = *(const s16x8*)(hl + l15 * 512 + ((kk * 64 + lhi * 16) ^ ((l15 & 7) << 4)));
#pragma unroll
    for (int kk = 0; kk < 4; ++kk) {
      acc0 = __builtin_amdgcn_mfma_f32_16x16x32_bf16(hf[kk], ur[kk * 2 + 0], acc0, 0, 0, 0);
      acc1 = __builtin_amdgcn_mfma_f32_16x16x32_bf16(hf[kk], ur[kk * 2 + 1], acc1, 0, 0, 0);
    }
#pragma unroll
    for (int kk = 4; kk < 8; ++kk) {
      s16x8 u0 = ulds[(w * 8 + (kk - 4) * 2 + 0) * 64 + l];
      s16x8 u1 = ulds[(w * 8 + (kk - 4) * 2 + 1) * 64 + l];
      acc0 = __builtin_amdgcn_mfma_f32_16x16x32_bf16(hf[kk], u0, acc0, 0, 0, 0);
      acc1 = __builtin_amdgcn_mfma_f32_16x16x32_bf16(hf[kk], u1, acc1, 0, 0, 0);
    }

    // ---- gates to LDS: sg[Q][row][col], col = sgs*32 + {0,16} + l15
#pragma unroll
    for (int r = 0; r < 4; ++r) {
      sg[(Q * 16 + lhi * 4 + r) * 66 + sgs * 32 + l15]      = acc0[r];
      sg[(Q * 16 + lhi * 4 + r) * 66 + sgs * 32 + 16 + l15] = acc1[r];
    }
    asm volatile("s_waitcnt lgkmcnt(0)" ::: "memory");
    __builtin_amdgcn_s_barrier();       // B: gates ready

    // ---- elementwise LSTM: 2 cells (row em, d = q*64 + 2*e5 + {0,1})
    {
      float gv[4][2];
#pragma unroll
      for (int Qq = 0; Qq < 4; ++Qq) {
        gv[Qq][0] = sg[(Qq * 16 + em) * 66 + 2 * e5];
        gv[Qq][1] = sg[(Qq * 16 + em) * 66 + 2 * e5 + 1];
      }
      const bool upd = (mk != 0);
      unsigned short hsv[2];
#pragma unroll
      for (int b = 0; b < 2; ++b) {
        float xi = b ? bh(xq.x) : bl(xq.x);
        float xf = b ? bh(xq.y) : bl(xq.y);
        float xc = b ? bh(xq.z) : bl(xq.z);
        float xo = b ? bh(xq.w) : bl(xq.w);
        float gi = gv[0][b] + xi + bq[0][b];
        float gf = gv[1][b] + xf + bq[1][b];
        float gc = gv[2][b] + xc + bq[2][b];
        float go = gv[3][b] + xo + bq[3][b];
        float i_ = fsigmoid(gi), f_ = fsigmoid(gf), o_ = fsigmoid(go);
        float cn = f_ * cc[b] + i_ * ftanh(gc);
        float hn = o_ * ftanh(cn);
        cc[b] = upd ? cn : cc[b];
        hh[b] = upd ? hn : hh[b];
        hsv[b] = __bfloat16_as_ushort(__float2bfloat16(hh[b]));
      }
      // publish tagged granule {2xbf16, t+1} (sc0sc1, fire-and-forget)
      u32x2 gr;
      gr.x = (unsigned)hsv[0] | ((unsigned)hsv[1] << 16);
      gr.y = (unsigned)(t + 1);
      char* pw = htag + (t & 1) * 65536 + (row0 + em) * 1024 + (q * 32 + e5) * 8;
      asm volatile("global_store_dwordx2 %0, %1, off sc0 sc1"
                   :: "v"(pw), "v"(gr) : "memory");
      // output store (fire-and-forget)
      float* op = out + ((size_t)(row0 + em) * L_ + t) * D_ + q * 64 + 2 * e5;
      op[0] = hh[0];
      op[1] = hh[1];
    }
  }

  // signal heaters
  if (tid == 0) {
    unsigned one = 1u;
    unsigned* df = donef + bid;
    asm volatile("global_store_dword %0, %1, off sc0 sc1"
                 :: "v"(df), "v"(one) : "memory");
  }
}

extern "C" void kernel_launch(void* const* d_in, const int* in_sizes, int n_in,
                              void* d_out, int out_size, void* d_ws, size_t ws_size,
                              hipStream_t stream) {
  const int*   ctx  = (const int*)d_in[0];
  const float* emb  = (const float*)d_in[1];
  const float* W    = (const float*)d_in[2];
  const float* U    = (const float*)d_in[3];
  const float* bias = (const float*)d_in[4];
  float* out = (float*)d_out;

  char* ws = (char*)d_ws;
  __hip_bfloat16* embb = (__hip_bfloat16*)(ws + OFF_EMBB);
  __hip_bfloat16* Wt   = (__hip_bfloat16*)(ws + OFF_WT);
  __hip_bfloat16* Uf   = (__hip_bfloat16*)(ws + OFF_UF);
  char*           htag = ws + OFF_HTAG;
  unsigned*       donef = (unsigned*)(ws + OFF_DONE);
  unsigned*       xgw  = (unsigned*)(ws + OFF_XG);
  unsigned char*  m8   = (unsigned char*)(ws + OFF_WT);   // reuse Wt after xg

  // per-launch resets (graph replays don't re-poison ws)
  hipMemsetAsync(htag, 0, 131072, stream);   // tag 0 == "h(-1)=0 ready"
  hipMemsetAsync(donef, 0, 64, stream);

  hipFuncSetAttribute((const void*)scan_kernel,
                      hipFuncAttributeMaxDynamicSharedMemorySize, SMEM_TOTAL);

  prep_kernel<<<1024, 256, 0, stream>>>(emb, W, U, embb, Wt, Uf);
  xg_kernel<<<512, 256, 0, stream>>>(ctx, embb, Wt, xgw);
  mask_kernel<<<128, 256, 0, stream>>>(ctx, m8);           // overwrites Wt (dead)
  scan_kernel<<<256, 512, SMEM_TOTAL, stream>>>(bias, Uf, xgw, m8, donef, htag, out);
}